// Round 5
// baseline (991.303 us; speedup 1.0000x reference)
//
#include <hip/hip_runtime.h>
#include <hip/hip_bf16.h>
#include <stdint.h>

// B=16, S=2048, D=64. All fp32 I/O; mask int32 (nonzero == masked -> -1e30).
// d_in: q[B,S,D] f32, k[B,S,D] f32, v[B,S,D] f32, mask[B,S,S] i32
// d_out: output[B,S,D] f32 (2097152 floats) then attn[B,S,S] f32.
//
// v5 path (needs 20 MB workspace):
//   prep_all (ONE kernel, 3 block-ranges): mask->bits, K->hi/lo frag, V->frag
//   attn_fused_v5: = proven v3/v4 structure with
//     - __launch_bounds__(512, 4): force VGPR+AGPR <= 128 -> 2 blocks/CU
//     - attn stores interleaved into the PV loop (store pipe overlaps MFMA)
//     - plain (non-nt) attn stores (v3-proven)
// Fallback: proven v1 kernel if ws too small.

#define S_DIM 2048
#define D_DIM 64

typedef short short8 __attribute__((ext_vector_type(8)));
typedef float floatx4 __attribute__((ext_vector_type(4)));
typedef unsigned short ushort8v __attribute__((ext_vector_type(8)));
typedef uint32_t u32a __attribute__((may_alias));

__device__ __forceinline__ unsigned short f2bf(float x) {
    uint32_t u = __float_as_uint(x);
    u += 0x7fffu + ((u >> 16) & 1u);
    return (unsigned short)(u >> 16);
}
__device__ __forceinline__ float bf2f(unsigned short h) {
    return __uint_as_float((uint32_t)h << 16);
}

// ---------------------------------------------------------------------------
// Fused prep. Grid 10240 x 256.
__global__ __launch_bounds__(256) void prep_all(
    const int* __restrict__ mask, uint32_t* __restrict__ bits,
    const float* __restrict__ k,
    unsigned short* __restrict__ khi2, unsigned short* __restrict__ klo2,
    const float* __restrict__ v, unsigned short* __restrict__ vfrag)
{
    const int blk = blockIdx.x;
    const int tid = threadIdx.x;

    if (blk < 8192) {
        // ---- mask -> bits (coalesced loads, ballot, 2-lane stores) ----
        const size_t base = (size_t)blk * 8192;
        const int lane = tid & 63;
        const size_t wbase = base + (size_t)(tid & ~63);
        #pragma unroll
        for (int j = 0; j < 32; ++j) {
            int m = mask[base + j * 256 + tid];
            unsigned long long bal = __ballot(m != 0);
            if ((lane & 31) == 0) {
                size_t wb = wbase + j * 256;            // multiple of 64
                bits[(wb >> 5) + (lane >> 5)] = (uint32_t)(bal >> ((lane >> 5) * 32));
            }
        }
    } else if (blk < 9216) {
        // ---- K -> hi/lo fragment order (2 kc per block) ----
        const int e  = blk - 8192;          // 0..1023
        const int b  = e >> 6;              // 64 blocks per batch
        const int kc = (e & 63) * 2 + (tid >> 7);
        const int t  = tid & 127;
        const int s = t >> 6, quad = (t >> 4) & 3, n16 = t & 15;
        const float* src = k + ((size_t)(b * S_DIM) + kc * 16 + n16) * D_DIM + s * 32 + quad * 8;
        float4 x0 = *(const float4*)src;
        float4 x1 = *(const float4*)(src + 4);
        float xs[8] = {x0.x, x0.y, x0.z, x0.w, x1.x, x1.y, x1.z, x1.w};
        ushort8v h, l;
        #pragma unroll
        for (int p = 0; p < 8; ++p) {
            unsigned short hp = f2bf(xs[p]);
            h[p] = hp;
            l[p] = f2bf(xs[p] - bf2f(hp));
        }
        size_t o = ((size_t)(b * 128 + kc)) * 1024 + (size_t)t * 8;
        *(ushort8v*)(khi2 + o) = h;
        *(ushort8v*)(klo2 + o) = l;
    } else {
        // ---- V -> PV fragment order ----
        const int e  = blk - 9216;          // 0..1023
        const int b  = e >> 6;
        const int kb = e & 63;
        const int nc = tid >> 6, quad = (tid >> 4) & 3, n16 = tid & 15;
        ushort8v o;
        #pragma unroll
        for (int p = 0; p < 8; ++p) {
            float x = v[((size_t)(b * S_DIM) + kb * 32 + quad * 8 + p) * D_DIM + nc * 16 + n16];
            o[p] = f2bf(x);
        }
        *(ushort8v*)(vfrag + ((size_t)(b * 64 + kb)) * 2048 + (size_t)tid * 8) = o;
    }
}

// ---------------------------------------------------------------------------
// Main kernel v5.
__global__ __launch_bounds__(512, 4) void attn_fused_v5(
    const float* __restrict__ q,
    const unsigned short* __restrict__ khi2, const unsigned short* __restrict__ klo2,
    const unsigned short* __restrict__ vfrag,
    const uint32_t* __restrict__ bits,
    float* __restrict__ out, float* __restrict__ attn)
{
    __shared__ __align__(16) float qlds[16 * 68];              // 4.4 KB
    __shared__ __align__(16) unsigned short pbuf[8 * 16 * 36]; // 9.2 KB (wave-private)
    __shared__ __align__(16) float obuf[8 * 16 * 68];          // 34.8 KB
    __shared__ float mxtab[8 * 16];
    __shared__ float ltab[8 * 16];

    const int tid  = threadIdx.x;
    const int w    = tid >> 6;
    const int lane = tid & 63;
    const int quad = lane >> 4;
    const int n16  = lane & 15;
    const int b    = blockIdx.x >> 7;     // 128 q-tiles per batch
    const int q0   = (blockIdx.x & 127) * 16;
    const int key0 = w * 256;

    // ---------------- bits prefetch: 8B per lane ---------------------------
    uint32_t blo, bhi;
    {
        const uint32_t* bsrc = bits +
            ((size_t)(b * S_DIM) + q0 + (lane >> 2)) * 64 + w * 8 + 2 * (lane & 3);
        uint2 bt = *(const uint2*)bsrc;
        blo = bt.x; bhi = bt.y;
    }

    // ---------------- Phase A: Q tile -> LDS, build A-frags (hi/lo) -------
    {
        int m = tid >> 5, d = (tid & 31) * 2;
        float2 qv = *(const float2*)(q + ((size_t)(b * S_DIM + q0 + m)) * D_DIM + d);
        qlds[m * 68 + d]     = qv.x;
        qlds[m * 68 + d + 1] = qv.y;
    }
    __syncthreads();

    short8 ahi[2], alo[2];
    #pragma unroll
    for (int s = 0; s < 2; ++s) {
        const float* qp = &qlds[n16 * 68 + s * 32 + quad * 8];
        union { unsigned short u[8]; short8 v; } H, L;
        #pragma unroll
        for (int p = 0; p < 8; ++p) {
            float x = qp[p];
            unsigned short hp = f2bf(x);
            H.u[p] = hp;
            L.u[p] = f2bf(x - bf2f(hp));
        }
        ahi[s] = H.v; alo[s] = L.v;
    }

    // ---------------- Phase B: scores = QK^T (frag-order K, coalesced) ----
    floatx4 sc[16];
    const unsigned short* khb = khi2 + (size_t)b * 131072;
    const unsigned short* klb = klo2 + (size_t)b * 131072;
    #pragma unroll
    for (int c = 0; c < 16; ++c) {
        const int kc = w * 16 + c;
        floatx4 acc = {0.f, 0.f, 0.f, 0.f};
        #pragma unroll
        for (int s = 0; s < 2; ++s) {
            const size_t off = (size_t)((kc * 2 + s) * 4 + quad) * 128 + n16 * 8;
            short8 BH = *(const short8*)(khb + off);
            short8 BL = *(const short8*)(klb + off);
            acc = __builtin_amdgcn_mfma_f32_16x16x32_bf16(ahi[s], BH, acc, 0, 0, 0);
            acc = __builtin_amdgcn_mfma_f32_16x16x32_bf16(ahi[s], BL, acc, 0, 0, 0);
            acc = __builtin_amdgcn_mfma_f32_16x16x32_bf16(alo[s], BH, acc, 0, 0, 0);
        }
        sc[c] = acc;
    }
    // mask + scale via in-register bitmask (shfl redistribution)
    #pragma unroll
    for (int r = 0; r < 4; ++r) {
        #pragma unroll
        for (int c = 0; c < 16; ++c) {
            int srcl = quad * 16 + r * 4 + (c >> 2);
            uint32_t d = (uint32_t)__shfl((int)((c & 2) ? bhi : blo), srcl, 64);
            uint32_t bit = (d >> ((c & 1) * 16 + n16)) & 1u;
            sc[c][r] = bit ? -1e30f : sc[c][r] * 0.125f;
        }
    }

    // ---------------- Phase C: exact softmax over 2048 keys ---------------
    #pragma unroll
    for (int r = 0; r < 4; ++r) {
        float mx = sc[0][r];
        #pragma unroll
        for (int c = 1; c < 16; ++c) mx = fmaxf(mx, sc[c][r]);
        #pragma unroll
        for (int o = 1; o < 16; o <<= 1) mx = fmaxf(mx, __shfl_xor(mx, o, 64));
        if (n16 == 0) mxtab[w * 16 + quad * 4 + r] = mx;
    }
    __syncthreads();
    #pragma unroll
    for (int r = 0; r < 4; ++r) {
        float mf = -3e38f;
        #pragma unroll
        for (int w2 = 0; w2 < 8; ++w2) mf = fmaxf(mf, mxtab[w2 * 16 + quad * 4 + r]);
        float l = 0.f;
        #pragma unroll
        for (int c = 0; c < 16; ++c) {
            float e = __expf(sc[c][r] - mf);
            sc[c][r] = e;
            l += e;
        }
        #pragma unroll
        for (int o = 1; o < 16; o <<= 1) l += __shfl_xor(l, o, 64);
        if (n16 == 0) ltab[w * 16 + quad * 4 + r] = l;
    }
    __syncthreads();
    #pragma unroll
    for (int r = 0; r < 4; ++r) {
        float l = 0.f;
        #pragma unroll
        for (int w2 = 0; w2 < 8; ++w2) l += ltab[w2 * 16 + quad * 4 + r];
        float inv = 1.0f / l;
        #pragma unroll
        for (int c = 0; c < 16; ++c) sc[c][r] *= inv;
    }

    // ---------------- Phase D+E fused: attn stores interleaved with PV ----
    // pbuf is wave-private (no barriers; may_alias keeps ds ordering).
    floatx4 o0 = {0,0,0,0}, o1 = {0,0,0,0}, o2 = {0,0,0,0}, o3 = {0,0,0,0};
    unsigned short* pw = pbuf + w * 576;   // 16 rows x 36 (32 keys + pad)
    const unsigned short* vtb = vfrag + (size_t)b * 131072;
    float* arow = attn + (size_t)(b * S_DIM + q0 + quad * 4) * S_DIM + key0 + n16;
    #pragma unroll
    for (int s2 = 0; s2 < 8; ++s2) {
        #pragma unroll
        for (int h = 0; h < 2; ++h) {
            const int c = s2 * 2 + h;
            #pragma unroll
            for (int r = 0; r < 4; ++r)
                pw[(quad * 4 + r) * 36 + h * 16 + n16] = f2bf(sc[c][r]);
        }
        short8 pa;
        {
            const u32a* pr = (const u32a*)((const char*)pbuf +
                                   (size_t)w * 1152 + n16 * 72 + quad * 16);
            union { uint32_t u[4]; short8 v; } P;
            P.u[0] = pr[0]; P.u[1] = pr[1]; P.u[2] = pr[2]; P.u[3] = pr[3];
            pa = P.v;
        }
        // attn stores for this chunk (overlap with MFMAs below)
        #pragma unroll
        for (int h = 0; h < 2; ++h) {
            const int c = s2 * 2 + h;
            #pragma unroll
            for (int r = 0; r < 4; ++r)
                arow[(size_t)r * S_DIM + c * 16] = sc[c][r];
        }
        const int kb = w * 8 + s2;
        #pragma unroll
        for (int nc = 0; nc < 4; ++nc) {
            const size_t off = (size_t)((kb * 4 + nc) * 4 + quad) * 128 + n16 * 8;
            short8 bv = *(const short8*)(vtb + off);
            floatx4& oo = (nc == 0 ? o0 : nc == 1 ? o1 : nc == 2 ? o2 : o3);
            oo = __builtin_amdgcn_mfma_f32_16x16x32_bf16(pa, bv, oo, 0, 0, 0);
        }
    }

    // ---------------- Phase F: reduce per-wave partial O, store -----------
    #pragma unroll
    for (int nc = 0; nc < 4; ++nc) {
        floatx4 oo = (nc == 0 ? o0 : nc == 1 ? o1 : nc == 2 ? o2 : o3);
        #pragma unroll
        for (int i = 0; i < 4; ++i)
            obuf[(w * 16 + quad * 4 + i) * 68 + nc * 16 + n16] = oo[i];
    }
    __syncthreads();
    #pragma unroll
    for (int t2 = 0; t2 < 2; ++t2) {
        int idx = tid + t2 * 512;
        int m = idx >> 6, d = idx & 63;
        float a = 0.f;
        #pragma unroll
        for (int w2 = 0; w2 < 8; ++w2) a += obuf[(w2 * 16 + m) * 68 + d];
        out[(size_t)(b * S_DIM + q0 + m) * D_DIM + d] = a;
    }
}

// ---------------------------------------------------------------------------
// Fallback v1 (proven) — used only if workspace is too small.
__global__ __launch_bounds__(512) void attn_fused_v1(
    const float* __restrict__ q, const float* __restrict__ k,
    const float* __restrict__ v, const int* __restrict__ mask,
    float* __restrict__ out, float* __restrict__ attn)
{
    __shared__ __align__(16) float qlds[16 * 68];
    __shared__ __align__(16) unsigned short pbuf[8 * 16 * 36];
    __shared__ __align__(16) float obuf[8 * 16 * 68];
    __shared__ float mxtab[8 * 16];
    __shared__ float ltab[8 * 16];

    const int tid  = threadIdx.x;
    const int w    = tid >> 6;
    const int lane = tid & 63;
    const int quad = lane >> 4;
    const int n16  = lane & 15;
    const int b    = blockIdx.x >> 7;
    const int q0   = (blockIdx.x & 127) * 16;
    const int key0 = w * 256;

    {
        int m = tid >> 5, d = (tid & 31) * 2;
        float2 qv = *(const float2*)(q + ((size_t)(b * S_DIM + q0 + m)) * D_DIM + d);
        qlds[m * 68 + d]     = qv.x;
        qlds[m * 68 + d + 1] = qv.y;
    }
    __syncthreads();

    short8 ahi[2], alo[2];
    #pragma unroll
    for (int s = 0; s < 2; ++s) {
        const float* qp = &qlds[n16 * 68 + s * 32 + quad * 8];
        union { __hip_bfloat162 h[4]; short8 v; } H, L;
        #pragma unroll
        for (int p = 0; p < 4; ++p) {
            float x0 = qp[2 * p], x1 = qp[2 * p + 1];
            __hip_bfloat162 h2 = __float22bfloat162_rn(float2{x0, x1});
            float l0 = x0 - __bfloat162float(h2.x);
            float l1 = x1 - __bfloat162float(h2.y);
            H.h[p] = h2;
            L.h[p] = __float22bfloat162_rn(float2{l0, l1});
        }
        ahi[s] = H.v; alo[s] = L.v;
    }

    floatx4 sc[16];
    const size_t kvbase = (size_t)(b * S_DIM) * D_DIM;
    #pragma unroll
    for (int c = 0; c < 16; ++c) {
        const int key = key0 + c * 16 + n16;
        const int* mp = mask + (size_t)(b * S_DIM + q0 + quad * 4) * S_DIM + key;
        int mk0 = mp[0], mk1 = mp[S_DIM], mk2 = mp[2 * S_DIM], mk3 = mp[3 * S_DIM];
        floatx4 acc = {0.f, 0.f, 0.f, 0.f};
        #pragma unroll
        for (int s = 0; s < 2; ++s) {
            const float* kp = k + kvbase + (size_t)key * D_DIM + s * 32 + quad * 8;
            float4 k0 = *(const float4*)kp;
            float4 k1 = *(const float4*)(kp + 4);
            float kf[8] = {k0.x, k0.y, k0.z, k0.w, k1.x, k1.y, k1.z, k1.w};
            union { __hip_bfloat162 h[4]; short8 v; } BH, BL;
            #pragma unroll
            for (int p = 0; p < 4; ++p) {
                float x0 = kf[2 * p], x1 = kf[2 * p + 1];
                __hip_bfloat162 h2 = __float22bfloat162_rn(float2{x0, x1});
                BH.h[p] = h2;
                BL.h[p] = __float22bfloat162_rn(
                    float2{x0 - __bfloat162float(h2.x), x1 - __bfloat162float(h2.y)});
            }
            acc = __builtin_amdgcn_mfma_f32_16x16x32_bf16(ahi[s], BH.v, acc, 0, 0, 0);
            acc = __builtin_amdgcn_mfma_f32_16x16x32_bf16(ahi[s], BL.v, acc, 0, 0, 0);
            acc = __builtin_amdgcn_mfma_f32_16x16x32_bf16(alo[s], BH.v, acc, 0, 0, 0);
        }
        sc[c][0] = mk0 ? -1e30f : acc[0] * 0.125f;
        sc[c][1] = mk1 ? -1e30f : acc[1] * 0.125f;
        sc[c][2] = mk2 ? -1e30f : acc[2] * 0.125f;
        sc[c][3] = mk3 ? -1e30f : acc[3] * 0.125f;
    }

    #pragma unroll
    for (int r = 0; r < 4; ++r) {
        float mx = sc[0][r];
        #pragma unroll
        for (int c = 1; c < 16; ++c) mx = fmaxf(mx, sc[c][r]);
        #pragma unroll
        for (int o = 1; o < 16; o <<= 1) mx = fmaxf(mx, __shfl_xor(mx, o, 64));
        if (n16 == 0) mxtab[w * 16 + quad * 4 + r] = mx;
    }
    __syncthreads();
    #pragma unroll
    for (int r = 0; r < 4; ++r) {
        float mf = -3e38f;
        #pragma unroll
        for (int w2 = 0; w2 < 8; ++w2) mf = fmaxf(mf, mxtab[w2 * 16 + quad * 4 + r]);
        float l = 0.f;
        #pragma unroll
        for (int c = 0; c < 16; ++c) {
            float e = __expf(sc[c][r] - mf);
            sc[c][r] = e;
            l += e;
        }
        #pragma unroll
        for (int o = 1; o < 16; o <<= 1) l += __shfl_xor(l, o, 64);
        if (n16 == 0) ltab[w * 16 + quad * 4 + r] = l;
    }
    __syncthreads();
    #pragma unroll
    for (int r = 0; r < 4; ++r) {
        float l = 0.f;
        #pragma unroll
        for (int w2 = 0; w2 < 8; ++w2) l += ltab[w2 * 16 + quad * 4 + r];
        float inv = 1.0f / l;
        #pragma unroll
        for (int c = 0; c < 16; ++c) sc[c][r] *= inv;
    }

    {
        float* arow = attn + (size_t)(b * S_DIM + q0 + quad * 4) * S_DIM + key0 + n16;
        #pragma unroll
        for (int c = 0; c < 16; ++c) {
            #pragma unroll
            for (int r = 0; r < 4; ++r) arow[(size_t)r * S_DIM + c * 16] = sc[c][r];
        }
    }

    floatx4 o0 = {0,0,0,0}, o1 = {0,0,0,0}, o2 = {0,0,0,0}, o3 = {0,0,0,0};
    unsigned short* pw = pbuf + w * 576;
    #pragma unroll
    for (int s2 = 0; s2 < 8; ++s2) {
        #pragma unroll
        for (int h = 0; h < 2; ++h) {
            const int c = s2 * 2 + h;
            #pragma unroll
            for (int r = 0; r < 4; ++r)
                pw[(quad * 4 + r) * 36 + h * 16 + n16] = f2bf(sc[c][r]);
        }
        __syncthreads();
        short8 pa;
        {
            const uint32_t* pr = (const uint32_t*)((const char*)pbuf +
                                   (size_t)w * 1152 + n16 * 72 + quad * 16);
            union { uint32_t u[4]; short8 v; } P;
            P.u[0] = pr[0]; P.u[1] = pr[1]; P.u[2] = pr[2]; P.u[3] = pr[3];
            pa = P.v;
        }
        const size_t vrow0 = (size_t)(b * S_DIM + key0 + s2 * 32 + quad * 8) * D_DIM;
        #pragma unroll
        for (int nc = 0; nc < 4; ++nc) {
            const float* vp = v + vrow0 + nc * 16 + n16;
            union { __hip_bfloat162 h[4]; short8 v8; } BV;
            #pragma unroll
            for (int p = 0; p < 4; ++p) {
                float x0 = vp[(size_t)(2 * p) * D_DIM];
                float x1 = vp[(size_t)(2 * p + 1) * D_DIM];
                BV.h[p] = __float22bfloat162_rn(float2{x0, x1});
            }
            floatx4& oo = (nc == 0 ? o0 : nc == 1 ? o1 : nc == 2 ? o2 : o3);
            oo = __builtin_amdgcn_mfma_f32_16x16x32_bf16(pa, BV.v8, oo, 0, 0, 0);
        }
        __syncthreads();
    }

    #pragma unroll
    for (int nc = 0; nc < 4; ++nc) {
        floatx4 oo = (nc == 0 ? o0 : nc == 1 ? o1 : nc == 2 ? o2 : o3);
        #pragma unroll
        for (int i = 0; i < 4; ++i)
            obuf[(w * 16 + quad * 4 + i) * 68 + nc * 16 + n16] = oo[i];
    }
    __syncthreads();
    #pragma unroll
    for (int t2 = 0; t2 < 2; ++t2) {
        int idx = tid + t2 * 512;
        int m = idx >> 6, d = idx & 63;
        float a = 0.f;
        #pragma unroll
        for (int w2 = 0; w2 < 8; ++w2) a += obuf[(w2 * 16 + m) * 68 + d];
        out[(size_t)(b * S_DIM + q0 + m) * D_DIM + d] = a;
    }
}

extern "C" void kernel_launch(void* const* d_in, const int* in_sizes, int n_in,
                              void* d_out, int out_size, void* d_ws, size_t ws_size,
                              hipStream_t stream) {
    const float* q    = (const float*)d_in[0];
    const float* k    = (const float*)d_in[1];
    const float* v    = (const float*)d_in[2];
    const int*   mask = (const int*)d_in[3];

    float* out  = (float*)d_out;
    float* attn = out + (size_t)16 * S_DIM * D_DIM;   // 2,097,152 floats

    const size_t NE = (size_t)16 * S_DIM * D_DIM;     // 2,097,152 elements
    const size_t need = NE * 2 * 3 + NE * 4;          // khi2+klo2+vfrag (bf16) + bits (u32) = 20 MB
    if (d_ws != nullptr && ws_size >= need) {
        unsigned short* khi2  = (unsigned short*)d_ws;
        unsigned short* klo2  = khi2 + NE;
        unsigned short* vfrag = klo2 + NE;
        uint32_t*       bits  = (uint32_t*)(vfrag + NE);
        prep_all<<<dim3(10240), dim3(256), 0, stream>>>(mask, bits, k, khi2, klo2, v, vfrag);
        attn_fused_v5<<<dim3(2048), dim3(512), 0, stream>>>(q, khi2, klo2, vfrag, bits, out, attn);
    } else {
        attn_fused_v1<<<dim3(2048), dim3(512), 0, stream>>>(q, k, v, mask, out, attn);
    }
}

// Round 6
// 557.731 us; speedup vs baseline: 1.7774x; 1.7774x over previous
//
#include <hip/hip_runtime.h>
#include <hip/hip_bf16.h>
#include <stdint.h>

// B=16, S=2048, D=64. All fp32 I/O; mask int32 (nonzero == masked -> -1e30).
// d_in: q[B,S,D] f32, k[B,S,D] f32, v[B,S,D] f32, mask[B,S,S] i32
// d_out: output[B,S,D] f32 (2097152 floats) then attn[B,S,S] f32.
//
// v6 path (needs 20 MB workspace):
//   prep_all (unchanged from v4): mask->bits, K->hi/lo frag, V->frag
//   attn_fused_v6: 16 waves/block, 128 keys/wave -> sc[8] (32 AGPR), total
//   regs ~110 < 128 so a 1024-thread block fits 4 waves/SIMD legitimately
//   (v5 lesson: capping regs below the accumulator size spills to scratch).
//   + XCD-aware block swizzle (each XCD L2 serves 2 batches).
// Fallback: proven v1 kernel if ws too small.

#define S_DIM 2048
#define D_DIM 64

typedef short short8 __attribute__((ext_vector_type(8)));
typedef float floatx4 __attribute__((ext_vector_type(4)));
typedef unsigned short ushort8v __attribute__((ext_vector_type(8)));
typedef uint32_t u32a __attribute__((may_alias));

__device__ __forceinline__ unsigned short f2bf(float x) {
    uint32_t u = __float_as_uint(x);
    u += 0x7fffu + ((u >> 16) & 1u);
    return (unsigned short)(u >> 16);
}
__device__ __forceinline__ float bf2f(unsigned short h) {
    return __uint_as_float((uint32_t)h << 16);
}

// ---------------------------------------------------------------------------
// Fused prep. Grid 10240 x 256. (unchanged, proven in v4)
__global__ __launch_bounds__(256) void prep_all(
    const int* __restrict__ mask, uint32_t* __restrict__ bits,
    const float* __restrict__ k,
    unsigned short* __restrict__ khi2, unsigned short* __restrict__ klo2,
    const float* __restrict__ v, unsigned short* __restrict__ vfrag)
{
    const int blk = blockIdx.x;
    const int tid = threadIdx.x;

    if (blk < 8192) {
        // ---- mask -> bits (coalesced loads, ballot, 2-lane stores) ----
        const size_t base = (size_t)blk * 8192;
        const int lane = tid & 63;
        const size_t wbase = base + (size_t)(tid & ~63);
        #pragma unroll
        for (int j = 0; j < 32; ++j) {
            int m = mask[base + j * 256 + tid];
            unsigned long long bal = __ballot(m != 0);
            if ((lane & 31) == 0) {
                size_t wb = wbase + j * 256;            // multiple of 64
                bits[(wb >> 5) + (lane >> 5)] = (uint32_t)(bal >> ((lane >> 5) * 32));
            }
        }
    } else if (blk < 9216) {
        // ---- K -> hi/lo fragment order (2 kc per block) ----
        const int e  = blk - 8192;          // 0..1023
        const int b  = e >> 6;              // 64 blocks per batch
        const int kc = (e & 63) * 2 + (tid >> 7);
        const int t  = tid & 127;
        const int s = t >> 6, quad = (t >> 4) & 3, n16 = t & 15;
        const float* src = k + ((size_t)(b * S_DIM) + kc * 16 + n16) * D_DIM + s * 32 + quad * 8;
        float4 x0 = *(const float4*)src;
        float4 x1 = *(const float4*)(src + 4);
        float xs[8] = {x0.x, x0.y, x0.z, x0.w, x1.x, x1.y, x1.z, x1.w};
        ushort8v h, l;
        #pragma unroll
        for (int p = 0; p < 8; ++p) {
            unsigned short hp = f2bf(xs[p]);
            h[p] = hp;
            l[p] = f2bf(xs[p] - bf2f(hp));
        }
        size_t o = ((size_t)(b * 128 + kc)) * 1024 + (size_t)t * 8;
        *(ushort8v*)(khi2 + o) = h;
        *(ushort8v*)(klo2 + o) = l;
    } else {
        // ---- V -> PV fragment order ----
        const int e  = blk - 9216;          // 0..1023
        const int b  = e >> 6;
        const int kb = e & 63;
        const int nc = tid >> 6, quad = (tid >> 4) & 3, n16 = tid & 15;
        ushort8v o;
        #pragma unroll
        for (int p = 0; p < 8; ++p) {
            float x = v[((size_t)(b * S_DIM) + kb * 32 + quad * 8 + p) * D_DIM + nc * 16 + n16];
            o[p] = f2bf(x);
        }
        *(ushort8v*)(vfrag + ((size_t)(b * 64 + kb)) * 2048 + (size_t)tid * 8) = o;
    }
}

// ---------------------------------------------------------------------------
// Main kernel v6: 16 waves, 128 keys/wave.
__global__ __launch_bounds__(1024) void attn_fused_v6(
    const float* __restrict__ q,
    const unsigned short* __restrict__ khi2, const unsigned short* __restrict__ klo2,
    const unsigned short* __restrict__ vfrag,
    const uint32_t* __restrict__ bits,
    float* __restrict__ out, float* __restrict__ attn)
{
    __shared__ __align__(16) float qlds[16 * 68];               // 4.4 KB
    __shared__ __align__(16) unsigned short pbuf[16 * 16 * 36]; // 18.4 KB (wave-private)
    __shared__ __align__(16) float obuf[8 * 16 * 68];           // 34.8 KB (paired reduce)
    __shared__ float mxtab[16 * 16];
    __shared__ float ltab[16 * 16];

    const int tid  = threadIdx.x;
    const int w    = tid >> 6;          // 0..15
    const int lane = tid & 63;
    const int quad = lane >> 4;
    const int n16  = lane & 15;
    const int wg   = blockIdx.x;
    const int swz  = (wg & 7) * 256 + (wg >> 3);   // XCD-contiguous: 2 batches/XCD
    const int b    = swz >> 7;
    const int q0   = (swz & 127) * 16;
    const int key0 = w * 128;

    // ---------------- bits prefetch: 1 dword per lane ----------------------
    // Wave needs rows q0..q0+15 x dwords [w*4, w*4+4). Lane l = row(l>>2)*4 + dw(l&3).
    uint32_t bmask = bits[((size_t)(b * S_DIM) + q0 + (lane >> 2)) * 64 + w * 4 + (lane & 3)];

    // ---------------- Phase A: Q tile -> LDS, build A-frags (hi/lo) -------
    {
        int m = tid >> 6, d = tid & 63;
        qlds[m * 68 + d] = q[((size_t)(b * S_DIM + q0 + m)) * D_DIM + d];
    }
    __syncthreads();

    short8 ahi[2], alo[2];
    #pragma unroll
    for (int s = 0; s < 2; ++s) {
        const float* qp = &qlds[n16 * 68 + s * 32 + quad * 8];
        union { unsigned short u[8]; short8 v; } H, L;
        #pragma unroll
        for (int p = 0; p < 8; ++p) {
            float x = qp[p];
            unsigned short hp = f2bf(x);
            H.u[p] = hp;
            L.u[p] = f2bf(x - bf2f(hp));
        }
        ahi[s] = H.v; alo[s] = L.v;
    }

    // ---------------- Phase B: scores = QK^T (frag-order K, coalesced) ----
    floatx4 sc[8];
    const unsigned short* khb = khi2 + (size_t)b * 131072;
    const unsigned short* klb = klo2 + (size_t)b * 131072;
    #pragma unroll
    for (int c = 0; c < 8; ++c) {
        const int kc = w * 8 + c;
        floatx4 acc = {0.f, 0.f, 0.f, 0.f};
        #pragma unroll
        for (int s = 0; s < 2; ++s) {
            const size_t off = (size_t)((kc * 2 + s) * 4 + quad) * 128 + n16 * 8;
            short8 BH = *(const short8*)(khb + off);
            short8 BL = *(const short8*)(klb + off);
            acc = __builtin_amdgcn_mfma_f32_16x16x32_bf16(ahi[s], BH, acc, 0, 0, 0);
            acc = __builtin_amdgcn_mfma_f32_16x16x32_bf16(ahi[s], BL, acc, 0, 0, 0);
            acc = __builtin_amdgcn_mfma_f32_16x16x32_bf16(alo[s], BH, acc, 0, 0, 0);
        }
        sc[c] = acc;
    }
    // mask + scale via in-register bitmask (shfl redistribution)
    // sc[c][r]: row_rel = quad*4+r, dw = c>>1, bit = (c&1)*16+n16,
    // source lane = row_rel*4 + dw.
    #pragma unroll
    for (int r = 0; r < 4; ++r) {
        #pragma unroll
        for (int c = 0; c < 8; ++c) {
            int srcl = (quad * 4 + r) * 4 + (c >> 1);
            uint32_t d = (uint32_t)__shfl((int)bmask, srcl, 64);
            uint32_t bit = (d >> ((c & 1) * 16 + n16)) & 1u;
            sc[c][r] = bit ? -1e30f : sc[c][r] * 0.125f;
        }
    }

    // ---------------- Phase C: exact softmax over 2048 keys ---------------
    #pragma unroll
    for (int r = 0; r < 4; ++r) {
        float mx = sc[0][r];
        #pragma unroll
        for (int c = 1; c < 8; ++c) mx = fmaxf(mx, sc[c][r]);
        #pragma unroll
        for (int o = 1; o < 16; o <<= 1) mx = fmaxf(mx, __shfl_xor(mx, o, 64));
        if (n16 == 0) mxtab[w * 16 + quad * 4 + r] = mx;
    }
    __syncthreads();
    #pragma unroll
    for (int r = 0; r < 4; ++r) {
        float mf = -3e38f;
        #pragma unroll
        for (int w2 = 0; w2 < 16; ++w2) mf = fmaxf(mf, mxtab[w2 * 16 + quad * 4 + r]);
        float l = 0.f;
        #pragma unroll
        for (int c = 0; c < 8; ++c) {
            float e = __expf(sc[c][r] - mf);
            sc[c][r] = e;
            l += e;
        }
        #pragma unroll
        for (int o = 1; o < 16; o <<= 1) l += __shfl_xor(l, o, 64);
        if (n16 == 0) ltab[w * 16 + quad * 4 + r] = l;
    }
    __syncthreads();
    #pragma unroll
    for (int r = 0; r < 4; ++r) {
        float l = 0.f;
        #pragma unroll
        for (int w2 = 0; w2 < 16; ++w2) l += ltab[w2 * 16 + quad * 4 + r];
        float inv = 1.0f / l;
        #pragma unroll
        for (int c = 0; c < 8; ++c) sc[c][r] *= inv;
    }

    // ---------------- Phase D: write attn (fp32, 64B-coalesced/quad) ------
    {
        float* arow = attn + (size_t)(b * S_DIM + q0 + quad * 4) * S_DIM + key0 + n16;
        #pragma unroll
        for (int c = 0; c < 8; ++c) {
            #pragma unroll
            for (int r = 0; r < 4; ++r) arow[(size_t)r * S_DIM + c * 16] = sc[c][r];
        }
    }

    // ---------------- Phase E: O += P*V, NO barriers (wave-private pbuf) --
    floatx4 o0 = {0,0,0,0}, o1 = {0,0,0,0}, o2 = {0,0,0,0}, o3 = {0,0,0,0};
    unsigned short* pw = pbuf + w * 576;   // 16 rows x 36 (32 keys + pad)
    const unsigned short* vtb = vfrag + (size_t)b * 131072;
    #pragma unroll
    for (int s2 = 0; s2 < 4; ++s2) {
        #pragma unroll
        for (int h = 0; h < 2; ++h) {
            const int c = s2 * 2 + h;
            #pragma unroll
            for (int r = 0; r < 4; ++r)
                pw[(quad * 4 + r) * 36 + h * 16 + n16] = f2bf(sc[c][r]);
        }
        short8 pa;
        {
            const u32a* pr = (const u32a*)((const char*)pbuf +
                                   (size_t)w * 1152 + n16 * 72 + quad * 16);
            union { uint32_t u[4]; short8 v; } P;
            P.u[0] = pr[0]; P.u[1] = pr[1]; P.u[2] = pr[2]; P.u[3] = pr[3];
            pa = P.v;
        }
        const int kb = w * 4 + s2;
        #pragma unroll
        for (int nc = 0; nc < 4; ++nc) {
            const size_t off = (size_t)((kb * 4 + nc) * 4 + quad) * 128 + n16 * 8;
            short8 bv = *(const short8*)(vtb + off);
            floatx4& oo = (nc == 0 ? o0 : nc == 1 ? o1 : nc == 2 ? o2 : o3);
            oo = __builtin_amdgcn_mfma_f32_16x16x32_bf16(pa, bv, oo, 0, 0, 0);
        }
    }

    // ---------------- Phase F: paired-wave reduce, then store --------------
    if (w < 8) {
        #pragma unroll
        for (int nc = 0; nc < 4; ++nc) {
            floatx4 oo = (nc == 0 ? o0 : nc == 1 ? o1 : nc == 2 ? o2 : o3);
            #pragma unroll
            for (int i = 0; i < 4; ++i)
                obuf[(w * 16 + quad * 4 + i) * 68 + nc * 16 + n16] = oo[i];
        }
    }
    __syncthreads();
    if (w >= 8) {
        #pragma unroll
        for (int nc = 0; nc < 4; ++nc) {
            floatx4 oo = (nc == 0 ? o0 : nc == 1 ? o1 : nc == 2 ? o2 : o3);
            #pragma unroll
            for (int i = 0; i < 4; ++i)
                obuf[((w - 8) * 16 + quad * 4 + i) * 68 + nc * 16 + n16] += oo[i];
        }
    }
    __syncthreads();
    {
        int m = tid >> 6, d = tid & 63;
        float a = 0.f;
        #pragma unroll
        for (int w2 = 0; w2 < 8; ++w2) a += obuf[(w2 * 16 + m) * 68 + d];
        out[(size_t)(b * S_DIM + q0 + m) * D_DIM + d] = a;
    }
}

// ---------------------------------------------------------------------------
// Fallback v1 (proven) — used only if workspace is too small.
__global__ __launch_bounds__(512) void attn_fused_v1(
    const float* __restrict__ q, const float* __restrict__ k,
    const float* __restrict__ v, const int* __restrict__ mask,
    float* __restrict__ out, float* __restrict__ attn)
{
    __shared__ __align__(16) float qlds[16 * 68];
    __shared__ __align__(16) unsigned short pbuf[8 * 16 * 36];
    __shared__ __align__(16) float obuf[8 * 16 * 68];
    __shared__ float mxtab[8 * 16];
    __shared__ float ltab[8 * 16];

    const int tid  = threadIdx.x;
    const int w    = tid >> 6;
    const int lane = tid & 63;
    const int quad = lane >> 4;
    const int n16  = lane & 15;
    const int b    = blockIdx.x >> 7;
    const int q0   = (blockIdx.x & 127) * 16;
    const int key0 = w * 256;

    {
        int m = tid >> 5, d = (tid & 31) * 2;
        float2 qv = *(const float2*)(q + ((size_t)(b * S_DIM + q0 + m)) * D_DIM + d);
        qlds[m * 68 + d]     = qv.x;
        qlds[m * 68 + d + 1] = qv.y;
    }
    __syncthreads();

    short8 ahi[2], alo[2];
    #pragma unroll
    for (int s = 0; s < 2; ++s) {
        const float* qp = &qlds[n16 * 68 + s * 32 + quad * 8];
        union { __hip_bfloat162 h[4]; short8 v; } H, L;
        #pragma unroll
        for (int p = 0; p < 4; ++p) {
            float x0 = qp[2 * p], x1 = qp[2 * p + 1];
            __hip_bfloat162 h2 = __float22bfloat162_rn(float2{x0, x1});
            float l0 = x0 - __bfloat162float(h2.x);
            float l1 = x1 - __bfloat162float(h2.y);
            H.h[p] = h2;
            L.h[p] = __float22bfloat162_rn(float2{l0, l1});
        }
        ahi[s] = H.v; alo[s] = L.v;
    }

    floatx4 sc[16];
    const size_t kvbase = (size_t)(b * S_DIM) * D_DIM;
    #pragma unroll
    for (int c = 0; c < 16; ++c) {
        const int key = key0 + c * 16 + n16;
        const int* mp = mask + (size_t)(b * S_DIM + q0 + quad * 4) * S_DIM + key;
        int mk0 = mp[0], mk1 = mp[S_DIM], mk2 = mp[2 * S_DIM], mk3 = mp[3 * S_DIM];
        floatx4 acc = {0.f, 0.f, 0.f, 0.f};
        #pragma unroll
        for (int s = 0; s < 2; ++s) {
            const float* kp = k + kvbase + (size_t)key * D_DIM + s * 32 + quad * 8;
            float4 k0 = *(const float4*)kp;
            float4 k1 = *(const float4*)(kp + 4);
            float kf[8] = {k0.x, k0.y, k0.z, k0.w, k1.x, k1.y, k1.z, k1.w};
            union { __hip_bfloat162 h[4]; short8 v; } BH, BL;
            #pragma unroll
            for (int p = 0; p < 4; ++p) {
                float x0 = kf[2 * p], x1 = kf[2 * p + 1];
                __hip_bfloat162 h2 = __float22bfloat162_rn(float2{x0, x1});
                BH.h[p] = h2;
                BL.h[p] = __float22bfloat162_rn(
                    float2{x0 - __bfloat162float(h2.x), x1 - __bfloat162float(h2.y)});
            }
            acc = __builtin_amdgcn_mfma_f32_16x16x32_bf16(ahi[s], BH.v, acc, 0, 0, 0);
            acc = __builtin_amdgcn_mfma_f32_16x16x32_bf16(ahi[s], BL.v, acc, 0, 0, 0);
            acc = __builtin_amdgcn_mfma_f32_16x16x32_bf16(alo[s], BH.v, acc, 0, 0, 0);
        }
        sc[c][0] = mk0 ? -1e30f : acc[0] * 0.125f;
        sc[c][1] = mk1 ? -1e30f : acc[1] * 0.125f;
        sc[c][2] = mk2 ? -1e30f : acc[2] * 0.125f;
        sc[c][3] = mk3 ? -1e30f : acc[3] * 0.125f;
    }

    #pragma unroll
    for (int r = 0; r < 4; ++r) {
        float mx = sc[0][r];
        #pragma unroll
        for (int c = 1; c < 16; ++c) mx = fmaxf(mx, sc[c][r]);
        #pragma unroll
        for (int o = 1; o < 16; o <<= 1) mx = fmaxf(mx, __shfl_xor(mx, o, 64));
        if (n16 == 0) mxtab[w * 16 + quad * 4 + r] = mx;
    }
    __syncthreads();
    #pragma unroll
    for (int r = 0; r < 4; ++r) {
        float mf = -3e38f;
        #pragma unroll
        for (int w2 = 0; w2 < 8; ++w2) mf = fmaxf(mf, mxtab[w2 * 16 + quad * 4 + r]);
        float l = 0.f;
        #pragma unroll
        for (int c = 0; c < 16; ++c) {
            float e = __expf(sc[c][r] - mf);
            sc[c][r] = e;
            l += e;
        }
        #pragma unroll
        for (int o = 1; o < 16; o <<= 1) l += __shfl_xor(l, o, 64);
        if (n16 == 0) ltab[w * 16 + quad * 4 + r] = l;
    }
    __syncthreads();
    #pragma unroll
    for (int r = 0; r < 4; ++r) {
        float l = 0.f;
        #pragma unroll
        for (int w2 = 0; w2 < 8; ++w2) l += ltab[w2 * 16 + quad * 4 + r];
        float inv = 1.0f / l;
        #pragma unroll
        for (int c = 0; c < 16; ++c) sc[c][r] *= inv;
    }

    {
        float* arow = attn + (size_t)(b * S_DIM + q0 + quad * 4) * S_DIM + key0 + n16;
        #pragma unroll
        for (int c = 0; c < 16; ++c) {
            #pragma unroll
            for (int r = 0; r < 4; ++r) arow[(size_t)r * S_DIM + c * 16] = sc[c][r];
        }
    }

    floatx4 o0 = {0,0,0,0}, o1 = {0,0,0,0}, o2 = {0,0,0,0}, o3 = {0,0,0,0};
    unsigned short* pw = pbuf + w * 576;
    #pragma unroll
    for (int s2 = 0; s2 < 8; ++s2) {
        #pragma unroll
        for (int h = 0; h < 2; ++h) {
            const int c = s2 * 2 + h;
            #pragma unroll
            for (int r = 0; r < 4; ++r)
                pw[(quad * 4 + r) * 36 + h * 16 + n16] = f2bf(sc[c][r]);
        }
        __syncthreads();
        short8 pa;
        {
            const uint32_t* pr = (const uint32_t*)((const char*)pbuf +
                                   (size_t)w * 1152 + n16 * 72 + quad * 16);
            union { uint32_t u[4]; short8 v; } P;
            P.u[0] = pr[0]; P.u[1] = pr[1]; P.u[2] = pr[2]; P.u[3] = pr[3];
            pa = P.v;
        }
        const size_t vrow0 = (size_t)(b * S_DIM + key0 + s2 * 32 + quad * 8) * D_DIM;
        #pragma unroll
        for (int nc = 0; nc < 4; ++nc) {
            const float* vp = v + vrow0 + nc * 16 + n16;
            union { __hip_bfloat162 h[4]; short8 v8; } BV;
            #pragma unroll
            for (int p = 0; p < 4; ++p) {
                float x0 = vp[(size_t)(2 * p) * D_DIM];
                float x1 = vp[(size_t)(2 * p + 1) * D_DIM];
                BV.h[p] = __float22bfloat162_rn(float2{x0, x1});
            }
            floatx4& oo = (nc == 0 ? o0 : nc == 1 ? o1 : nc == 2 ? o2 : o3);
            oo = __builtin_amdgcn_mfma_f32_16x16x32_bf16(pa, BV.v8, oo, 0, 0, 0);
        }
        __syncthreads();
    }

    #pragma unroll
    for (int nc = 0; nc < 4; ++nc) {
        floatx4 oo = (nc == 0 ? o0 : nc == 1 ? o1 : nc == 2 ? o2 : o3);
        #pragma unroll
        for (int i = 0; i < 4; ++i)
            obuf[(w * 16 + quad * 4 + i) * 68 + nc * 16 + n16] = oo[i];
    }
    __syncthreads();
    #pragma unroll
    for (int t2 = 0; t2 < 2; ++t2) {
        int idx = tid + t2 * 512;
        int m = idx >> 6, d = idx & 63;
        float a = 0.f;
        #pragma unroll
        for (int w2 = 0; w2 < 8; ++w2) a += obuf[(w2 * 16 + m) * 68 + d];
        out[(size_t)(b * S_DIM + q0 + m) * D_DIM + d] = a;
    }
}

extern "C" void kernel_launch(void* const* d_in, const int* in_sizes, int n_in,
                              void* d_out, int out_size, void* d_ws, size_t ws_size,
                              hipStream_t stream) {
    const float* q    = (const float*)d_in[0];
    const float* k    = (const float*)d_in[1];
    const float* v    = (const float*)d_in[2];
    const int*   mask = (const int*)d_in[3];

    float* out  = (float*)d_out;
    float* attn = out + (size_t)16 * S_DIM * D_DIM;   // 2,097,152 floats

    const size_t NE = (size_t)16 * S_DIM * D_DIM;     // 2,097,152 elements
    const size_t need = NE * 2 * 3 + NE * 4;          // khi2+klo2+vfrag (bf16) + bits (u32) = 20 MB
    if (d_ws != nullptr && ws_size >= need) {
        unsigned short* khi2  = (unsigned short*)d_ws;
        unsigned short* klo2  = khi2 + NE;
        unsigned short* vfrag = klo2 + NE;
        uint32_t*       bits  = (uint32_t*)(vfrag + NE);
        prep_all<<<dim3(10240), dim3(256), 0, stream>>>(mask, bits, k, khi2, klo2, v, vfrag);
        attn_fused_v6<<<dim3(2048), dim3(1024), 0, stream>>>(q, khi2, klo2, vfrag, bits, out, attn);
    } else {
        attn_fused_v1<<<dim3(2048), dim3(512), 0, stream>>>(q, k, v, mask, out, attn);
    }
}

// Round 7
// 556.014 us; speedup vs baseline: 1.7829x; 1.0031x over previous
//
#include <hip/hip_runtime.h>
#include <hip/hip_bf16.h>
#include <stdint.h>

// B=16, S=2048, D=64. All fp32 I/O; mask int32 (nonzero == masked -> -1e30).
// d_in: q[B,S,D] f32, k[B,S,D] f32, v[B,S,D] f32, mask[B,S,S] i32
// d_out: output[B,S,D] f32 (2097152 floats) then attn[B,S,S] f32.
//
// v7 path (needs 12 MB workspace):
//   prep_kv: K -> hi/lo bf16 frag order, V -> bf16 PV frag order (2048 blocks)
//   attn_fused_v7: v6 structure (16 waves, 128 keys/wave, sc[8]) with the
//   mask read folded INTO the main kernel: 8 coalesced dwordx4 loads/lane
//   issued before Phase A (latency hidden under Q staging), ballot-compressed
//   to 1 word/lane, applied via 4 shfls + bit-extract. Removes the serial
//   268 MB mask prepass (~50 us) — main kernel has ~5 TB/s BW slack to
//   absorb the ride-along read.
// Fallback: proven v1 kernel if ws too small.

#define S_DIM 2048
#define D_DIM 64

typedef short short8 __attribute__((ext_vector_type(8)));
typedef float floatx4 __attribute__((ext_vector_type(4)));
typedef unsigned short ushort8v __attribute__((ext_vector_type(8)));
typedef uint32_t u32a __attribute__((may_alias));

__device__ __forceinline__ unsigned short f2bf(float x) {
    uint32_t u = __float_as_uint(x);
    u += 0x7fffu + ((u >> 16) & 1u);
    return (unsigned short)(u >> 16);
}
__device__ __forceinline__ float bf2f(unsigned short h) {
    return __uint_as_float((uint32_t)h << 16);
}

// ---------------------------------------------------------------------------
// K/V prep. Grid 2048 x 256. (formulas proven in v4/v6)
__global__ __launch_bounds__(256) void prep_kv(
    const float* __restrict__ k,
    unsigned short* __restrict__ khi2, unsigned short* __restrict__ klo2,
    const float* __restrict__ v, unsigned short* __restrict__ vfrag)
{
    const int blk = blockIdx.x;
    const int tid = threadIdx.x;

    if (blk < 1024) {
        // ---- K -> hi/lo fragment order (2 kc per block) ----
        const int e  = blk;                 // 0..1023
        const int b  = e >> 6;              // 64 blocks per batch
        const int kc = (e & 63) * 2 + (tid >> 7);
        const int t  = tid & 127;
        const int s = t >> 6, quad = (t >> 4) & 3, n16 = t & 15;
        const float* src = k + ((size_t)(b * S_DIM) + kc * 16 + n16) * D_DIM + s * 32 + quad * 8;
        float4 x0 = *(const float4*)src;
        float4 x1 = *(const float4*)(src + 4);
        float xs[8] = {x0.x, x0.y, x0.z, x0.w, x1.x, x1.y, x1.z, x1.w};
        ushort8v h, l;
        #pragma unroll
        for (int p = 0; p < 8; ++p) {
            unsigned short hp = f2bf(xs[p]);
            h[p] = hp;
            l[p] = f2bf(xs[p] - bf2f(hp));
        }
        size_t o = ((size_t)(b * 128 + kc)) * 1024 + (size_t)t * 8;
        *(ushort8v*)(khi2 + o) = h;
        *(ushort8v*)(klo2 + o) = l;
    } else {
        // ---- V -> PV fragment order ----
        const int e  = blk - 1024;          // 0..1023
        const int b  = e >> 6;
        const int kb = e & 63;
        const int nc = tid >> 6, quad = (tid >> 4) & 3, n16 = tid & 15;
        ushort8v o;
        #pragma unroll
        for (int p = 0; p < 8; ++p) {
            float x = v[((size_t)(b * S_DIM) + kb * 32 + quad * 8 + p) * D_DIM + nc * 16 + n16];
            o[p] = f2bf(x);
        }
        *(ushort8v*)(vfrag + ((size_t)(b * 64 + kb)) * 2048 + (size_t)tid * 8) = o;
    }
}

// ---------------------------------------------------------------------------
// Main kernel v7: 16 waves, 128 keys/wave, in-kernel mask compress.
__global__ __launch_bounds__(1024) void attn_fused_v7(
    const float* __restrict__ q,
    const unsigned short* __restrict__ khi2, const unsigned short* __restrict__ klo2,
    const unsigned short* __restrict__ vfrag,
    const int* __restrict__ mask,
    float* __restrict__ out, float* __restrict__ attn)
{
    __shared__ __align__(16) float qlds[16 * 68];               // 4.4 KB
    __shared__ __align__(16) unsigned short pbuf[16 * 16 * 36]; // 18.4 KB (wave-private)
    __shared__ __align__(16) float obuf[8 * 16 * 68];           // 34.8 KB (paired reduce)
    __shared__ float mxtab[16 * 16];
    __shared__ float ltab[16 * 16];

    const int tid  = threadIdx.x;
    const int w    = tid >> 6;          // 0..15
    const int lane = tid & 63;
    const int quad = lane >> 4;
    const int n16  = lane & 15;
    const int wg   = blockIdx.x;
    const int swz  = (wg & 7) * 256 + (wg >> 3);   // XCD-contiguous: 2 batches/XCD
    const int b    = swz >> 7;
    const int q0   = (swz & 127) * 16;
    const int key0 = w * 128;

    // ---------------- Phase M: issue mask loads (coalesced, 8x dwordx4) ----
    // Wave w covers rows q0..q0+15, keys [w*128, w*128+128).
    // Iter it: lane l loads row 2*it + (l>>5), keys 4*(l&31) .. +4 (rel).
    int4 mx[8];
    {
        const int* mrow = mask + ((size_t)(b * S_DIM) + q0 + (lane >> 5)) * S_DIM
                               + key0 + (lane & 31) * 4;
        #pragma unroll
        for (int it = 0; it < 8; ++it)
            mx[it] = *(const int4*)(mrow + (size_t)(2 * it) * S_DIM);
    }

    // ---------------- Phase A: Q tile -> LDS, build A-frags (hi/lo) -------
    {
        int m = tid >> 6, d = tid & 63;
        qlds[m * 68 + d] = q[((size_t)(b * S_DIM + q0 + m)) * D_DIM + d];
    }
    __syncthreads();

    short8 ahi[2], alo[2];
    #pragma unroll
    for (int s = 0; s < 2; ++s) {
        const float* qp = &qlds[n16 * 68 + s * 32 + quad * 8];
        union { unsigned short u[8]; short8 v; } H, L;
        #pragma unroll
        for (int p = 0; p < 8; ++p) {
            float x = qp[p];
            unsigned short hp = f2bf(x);
            H.u[p] = hp;
            L.u[p] = f2bf(x - bf2f(hp));
        }
        ahi[s] = H.v; alo[s] = L.v;
    }

    // ---------------- Phase M2: ballot-compress mask -> 1 word/lane --------
    // kept @ lane l = bits a in [0,32): mask[row l>>2][key 4a + (l&3)] != 0
    uint32_t kept = 0;
    {
        const int lr = lane >> 2;   // this lane's word: row
        const int le = lane & 3;    // this lane's word: key phase
        #pragma unroll
        for (int it = 0; it < 8; ++it) {
            #pragma unroll
            for (int e = 0; e < 4; ++e) {
                int val = (e == 0 ? mx[it].x : e == 1 ? mx[it].y
                         : e == 2 ? mx[it].z : mx[it].w);
                unsigned long long bal = __ballot(val != 0);
                if (lr == 2 * it && le == e)     kept = (uint32_t)bal;
                if (lr == 2 * it + 1 && le == e) kept = (uint32_t)(bal >> 32);
            }
        }
    }

    // ---------------- Phase B: scores = QK^T (frag-order K, coalesced) ----
    floatx4 sc[8];
    const unsigned short* khb = khi2 + (size_t)b * 131072;
    const unsigned short* klb = klo2 + (size_t)b * 131072;
    #pragma unroll
    for (int c = 0; c < 8; ++c) {
        const int kc = w * 8 + c;
        floatx4 acc = {0.f, 0.f, 0.f, 0.f};
        #pragma unroll
        for (int s = 0; s < 2; ++s) {
            const size_t off = (size_t)((kc * 2 + s) * 4 + quad) * 128 + n16 * 8;
            short8 BH = *(const short8*)(khb + off);
            short8 BL = *(const short8*)(klb + off);
            acc = __builtin_amdgcn_mfma_f32_16x16x32_bf16(ahi[s], BH, acc, 0, 0, 0);
            acc = __builtin_amdgcn_mfma_f32_16x16x32_bf16(ahi[s], BL, acc, 0, 0, 0);
            acc = __builtin_amdgcn_mfma_f32_16x16x32_bf16(alo[s], BH, acc, 0, 0, 0);
        }
        sc[c] = acc;
    }
    // mask + scale: sc[c][r] needs mask[row quad*4+r][key c*16+n16]
    //   = word(row, e=n16&3) bit (4c + (n16>>2)); word lives at lane row*4+e.
    #pragma unroll
    for (int r = 0; r < 4; ++r) {
        int srcl = (quad * 4 + r) * 4 + (n16 & 3);
        uint32_t wd = (uint32_t)__shfl((int)kept, srcl, 64);
        #pragma unroll
        for (int c = 0; c < 8; ++c) {
            uint32_t bit = (wd >> (c * 4 + (n16 >> 2))) & 1u;
            sc[c][r] = bit ? -1e30f : sc[c][r] * 0.125f;
        }
    }

    // ---------------- Phase C: exact softmax over 2048 keys ---------------
    #pragma unroll
    for (int r = 0; r < 4; ++r) {
        float mxv = sc[0][r];
        #pragma unroll
        for (int c = 1; c < 8; ++c) mxv = fmaxf(mxv, sc[c][r]);
        #pragma unroll
        for (int o = 1; o < 16; o <<= 1) mxv = fmaxf(mxv, __shfl_xor(mxv, o, 64));
        if (n16 == 0) mxtab[w * 16 + quad * 4 + r] = mxv;
    }
    __syncthreads();
    #pragma unroll
    for (int r = 0; r < 4; ++r) {
        float mf = -3e38f;
        #pragma unroll
        for (int w2 = 0; w2 < 16; ++w2) mf = fmaxf(mf, mxtab[w2 * 16 + quad * 4 + r]);
        float l = 0.f;
        #pragma unroll
        for (int c = 0; c < 8; ++c) {
            float e = __expf(sc[c][r] - mf);
            sc[c][r] = e;
            l += e;
        }
        #pragma unroll
        for (int o = 1; o < 16; o <<= 1) l += __shfl_xor(l, o, 64);
        if (n16 == 0) ltab[w * 16 + quad * 4 + r] = l;
    }
    __syncthreads();
    #pragma unroll
    for (int r = 0; r < 4; ++r) {
        float l = 0.f;
        #pragma unroll
        for (int w2 = 0; w2 < 16; ++w2) l += ltab[w2 * 16 + quad * 4 + r];
        float inv = 1.0f / l;
        #pragma unroll
        for (int c = 0; c < 8; ++c) sc[c][r] *= inv;
    }

    // ---------------- Phase D: write attn (fp32, 64B-coalesced/quad) ------
    {
        float* arow = attn + (size_t)(b * S_DIM + q0 + quad * 4) * S_DIM + key0 + n16;
        #pragma unroll
        for (int c = 0; c < 8; ++c) {
            #pragma unroll
            for (int r = 0; r < 4; ++r) arow[(size_t)r * S_DIM + c * 16] = sc[c][r];
        }
    }

    // ---------------- Phase E: O += P*V, NO barriers (wave-private pbuf) --
    floatx4 o0 = {0,0,0,0}, o1 = {0,0,0,0}, o2 = {0,0,0,0}, o3 = {0,0,0,0};
    unsigned short* pw = pbuf + w * 576;   // 16 rows x 36 (32 keys + pad)
    const unsigned short* vtb = vfrag + (size_t)b * 131072;
    #pragma unroll
    for (int s2 = 0; s2 < 4; ++s2) {
        #pragma unroll
        for (int h = 0; h < 2; ++h) {
            const int c = s2 * 2 + h;
            #pragma unroll
            for (int r = 0; r < 4; ++r)
                pw[(quad * 4 + r) * 36 + h * 16 + n16] = f2bf(sc[c][r]);
        }
        short8 pa;
        {
            const u32a* pr = (const u32a*)((const char*)pbuf +
                                   (size_t)w * 1152 + n16 * 72 + quad * 16);
            union { uint32_t u[4]; short8 v; } P;
            P.u[0] = pr[0]; P.u[1] = pr[1]; P.u[2] = pr[2]; P.u[3] = pr[3];
            pa = P.v;
        }
        const int kb = w * 4 + s2;
        #pragma unroll
        for (int nc = 0; nc < 4; ++nc) {
            const size_t off = (size_t)((kb * 4 + nc) * 4 + quad) * 128 + n16 * 8;
            short8 bv = *(const short8*)(vtb + off);
            floatx4& oo = (nc == 0 ? o0 : nc == 1 ? o1 : nc == 2 ? o2 : o3);
            oo = __builtin_amdgcn_mfma_f32_16x16x32_bf16(pa, bv, oo, 0, 0, 0);
        }
    }

    // ---------------- Phase F: paired-wave reduce, then store --------------
    if (w < 8) {
        #pragma unroll
        for (int nc = 0; nc < 4; ++nc) {
            floatx4 oo = (nc == 0 ? o0 : nc == 1 ? o1 : nc == 2 ? o2 : o3);
            #pragma unroll
            for (int i = 0; i < 4; ++i)
                obuf[(w * 16 + quad * 4 + i) * 68 + nc * 16 + n16] = oo[i];
        }
    }
    __syncthreads();
    if (w >= 8) {
        #pragma unroll
        for (int nc = 0; nc < 4; ++nc) {
            floatx4 oo = (nc == 0 ? o0 : nc == 1 ? o1 : nc == 2 ? o2 : o3);
            #pragma unroll
            for (int i = 0; i < 4; ++i)
                obuf[((w - 8) * 16 + quad * 4 + i) * 68 + nc * 16 + n16] += oo[i];
        }
    }
    __syncthreads();
    {
        int m = tid >> 6, d = tid & 63;
        float a = 0.f;
        #pragma unroll
        for (int w2 = 0; w2 < 8; ++w2) a += obuf[(w2 * 16 + m) * 68 + d];
        out[(size_t)(b * S_DIM + q0 + m) * D_DIM + d] = a;
    }
}

// ---------------------------------------------------------------------------
// Fallback v1 (proven) — used only if workspace is too small.
__global__ __launch_bounds__(512) void attn_fused_v1(
    const float* __restrict__ q, const float* __restrict__ k,
    const float* __restrict__ v, const int* __restrict__ mask,
    float* __restrict__ out, float* __restrict__ attn)
{
    __shared__ __align__(16) float qlds[16 * 68];
    __shared__ __align__(16) unsigned short pbuf[8 * 16 * 36];
    __shared__ __align__(16) float obuf[8 * 16 * 68];
    __shared__ float mxtab[8 * 16];
    __shared__ float ltab[8 * 16];

    const int tid  = threadIdx.x;
    const int w    = tid >> 6;
    const int lane = tid & 63;
    const int quad = lane >> 4;
    const int n16  = lane & 15;
    const int b    = blockIdx.x >> 7;
    const int q0   = (blockIdx.x & 127) * 16;
    const int key0 = w * 256;

    {
        int m = tid >> 5, d = (tid & 31) * 2;
        float2 qv = *(const float2*)(q + ((size_t)(b * S_DIM + q0 + m)) * D_DIM + d);
        qlds[m * 68 + d]     = qv.x;
        qlds[m * 68 + d + 1] = qv.y;
    }
    __syncthreads();

    short8 ahi[2], alo[2];
    #pragma unroll
    for (int s = 0; s < 2; ++s) {
        const float* qp = &qlds[n16 * 68 + s * 32 + quad * 8];
        union { __hip_bfloat162 h[4]; short8 v; } H, L;
        #pragma unroll
        for (int p = 0; p < 4; ++p) {
            float x0 = qp[2 * p], x1 = qp[2 * p + 1];
            __hip_bfloat162 h2 = __float22bfloat162_rn(float2{x0, x1});
            float l0 = x0 - __bfloat162float(h2.x);
            float l1 = x1 - __bfloat162float(h2.y);
            H.h[p] = h2;
            L.h[p] = __float22bfloat162_rn(float2{l0, l1});
        }
        ahi[s] = H.v; alo[s] = L.v;
    }

    floatx4 sc[16];
    const size_t kvbase = (size_t)(b * S_DIM) * D_DIM;
    #pragma unroll
    for (int c = 0; c < 16; ++c) {
        const int key = key0 + c * 16 + n16;
        const int* mp = mask + (size_t)(b * S_DIM + q0 + quad * 4) * S_DIM + key;
        int mk0 = mp[0], mk1 = mp[S_DIM], mk2 = mp[2 * S_DIM], mk3 = mp[3 * S_DIM];
        floatx4 acc = {0.f, 0.f, 0.f, 0.f};
        #pragma unroll
        for (int s = 0; s < 2; ++s) {
            const float* kp = k + kvbase + (size_t)key * D_DIM + s * 32 + quad * 8;
            float4 k0 = *(const float4*)kp;
            float4 k1 = *(const float4*)(kp + 4);
            float kf[8] = {k0.x, k0.y, k0.z, k0.w, k1.x, k1.y, k1.z, k1.w};
            union { __hip_bfloat162 h[4]; short8 v; } BH, BL;
            #pragma unroll
            for (int p = 0; p < 4; ++p) {
                float x0 = kf[2 * p], x1 = kf[2 * p + 1];
                __hip_bfloat162 h2 = __float22bfloat162_rn(float2{x0, x1});
                BH.h[p] = h2;
                BL.h[p] = __float22bfloat162_rn(
                    float2{x0 - __bfloat162float(h2.x), x1 - __bfloat162float(h2.y)});
            }
            acc = __builtin_amdgcn_mfma_f32_16x16x32_bf16(ahi[s], BH.v, acc, 0, 0, 0);
            acc = __builtin_amdgcn_mfma_f32_16x16x32_bf16(ahi[s], BL.v, acc, 0, 0, 0);
            acc = __builtin_amdgcn_mfma_f32_16x16x32_bf16(alo[s], BH.v, acc, 0, 0, 0);
        }
        sc[c][0] = mk0 ? -1e30f : acc[0] * 0.125f;
        sc[c][1] = mk1 ? -1e30f : acc[1] * 0.125f;
        sc[c][2] = mk2 ? -1e30f : acc[2] * 0.125f;
        sc[c][3] = mk3 ? -1e30f : acc[3] * 0.125f;
    }

    #pragma unroll
    for (int r = 0; r < 4; ++r) {
        float mx = sc[0][r];
        #pragma unroll
        for (int c = 1; c < 16; ++c) mx = fmaxf(mx, sc[c][r]);
        #pragma unroll
        for (int o = 1; o < 16; o <<= 1) mx = fmaxf(mx, __shfl_xor(mx, o, 64));
        if (n16 == 0) mxtab[w * 16 + quad * 4 + r] = mx;
    }
    __syncthreads();
    #pragma unroll
    for (int r = 0; r < 4; ++r) {
        float mf = -3e38f;
        #pragma unroll
        for (int w2 = 0; w2 < 8; ++w2) mf = fmaxf(mf, mxtab[w2 * 16 + quad * 4 + r]);
        float l = 0.f;
        #pragma unroll
        for (int c = 0; c < 16; ++c) {
            float e = __expf(sc[c][r] - mf);
            sc[c][r] = e;
            l += e;
        }
        #pragma unroll
        for (int o = 1; o < 16; o <<= 1) l += __shfl_xor(l, o, 64);
        if (n16 == 0) ltab[w * 16 + quad * 4 + r] = l;
    }
    __syncthreads();
    #pragma unroll
    for (int r = 0; r < 4; ++r) {
        float l = 0.f;
        #pragma unroll
        for (int w2 = 0; w2 < 8; ++w2) l += ltab[w2 * 16 + quad * 4 + r];
        float inv = 1.0f / l;
        #pragma unroll
        for (int c = 0; c < 16; ++c) sc[c][r] *= inv;
    }

    {
        float* arow = attn + (size_t)(b * S_DIM + q0 + quad * 4) * S_DIM + key0 + n16;
        #pragma unroll
        for (int c = 0; c < 16; ++c) {
            #pragma unroll
            for (int r = 0; r < 4; ++r) arow[(size_t)r * S_DIM + c * 16] = sc[c][r];
        }
    }

    floatx4 o0 = {0,0,0,0}, o1 = {0,0,0,0}, o2 = {0,0,0,0}, o3 = {0,0,0,0};
    unsigned short* pw = pbuf + w * 576;
    #pragma unroll
    for (int s2 = 0; s2 < 8; ++s2) {
        #pragma unroll
        for (int h = 0; h < 2; ++h) {
            const int c = s2 * 2 + h;
            #pragma unroll
            for (int r = 0; r < 4; ++r)
                pw[(quad * 4 + r) * 36 + h * 16 + n16] = f2bf(sc[c][r]);
        }
        __syncthreads();
        short8 pa;
        {
            const uint32_t* pr = (const uint32_t*)((const char*)pbuf +
                                   (size_t)w * 1152 + n16 * 72 + quad * 16);
            union { uint32_t u[4]; short8 v; } P;
            P.u[0] = pr[0]; P.u[1] = pr[1]; P.u[2] = pr[2]; P.u[3] = pr[3];
            pa = P.v;
        }
        const size_t vrow0 = (size_t)(b * S_DIM + key0 + s2 * 32 + quad * 8) * D_DIM;
        #pragma unroll
        for (int nc = 0; nc < 4; ++nc) {
            const float* vp = v + vrow0 + nc * 16 + n16;
            union { __hip_bfloat162 h[4]; short8 v8; } BV;
            #pragma unroll
            for (int p = 0; p < 4; ++p) {
                float x0 = vp[(size_t)(2 * p) * D_DIM];
                float x1 = vp[(size_t)(2 * p + 1) * D_DIM];
                BV.h[p] = __float22bfloat162_rn(float2{x0, x1});
            }
            floatx4& oo = (nc == 0 ? o0 : nc == 1 ? o1 : nc == 2 ? o2 : o3);
            oo = __builtin_amdgcn_mfma_f32_16x16x32_bf16(pa, BV.v8, oo, 0, 0, 0);
        }
        __syncthreads();
    }

    #pragma unroll
    for (int nc = 0; nc < 4; ++nc) {
        floatx4 oo = (nc == 0 ? o0 : nc == 1 ? o1 : nc == 2 ? o2 : o3);
        #pragma unroll
        for (int i = 0; i < 4; ++i)
            obuf[(w * 16 + quad * 4 + i) * 68 + nc * 16 + n16] = oo[i];
    }
    __syncthreads();
    #pragma unroll
    for (int t2 = 0; t2 < 2; ++t2) {
        int idx = tid + t2 * 512;
        int m = idx >> 6, d = idx & 63;
        float a = 0.f;
        #pragma unroll
        for (int w2 = 0; w2 < 8; ++w2) a += obuf[(w2 * 16 + m) * 68 + d];
        out[(size_t)(b * S_DIM + q0 + m) * D_DIM + d] = a;
    }
}

extern "C" void kernel_launch(void* const* d_in, const int* in_sizes, int n_in,
                              void* d_out, int out_size, void* d_ws, size_t ws_size,
                              hipStream_t stream) {
    const float* q    = (const float*)d_in[0];
    const float* k    = (const float*)d_in[1];
    const float* v    = (const float*)d_in[2];
    const int*   mask = (const int*)d_in[3];

    float* out  = (float*)d_out;
    float* attn = out + (size_t)16 * S_DIM * D_DIM;   // 2,097,152 floats

    const size_t NE = (size_t)16 * S_DIM * D_DIM;     // 2,097,152 elements
    const size_t need = NE * 2 * 3;                   // khi2+klo2+vfrag (bf16) = 12 MB
    if (d_ws != nullptr && ws_size >= need) {
        unsigned short* khi2  = (unsigned short*)d_ws;
        unsigned short* klo2  = khi2 + NE;
        unsigned short* vfrag = klo2 + NE;
        prep_kv<<<dim3(2048), dim3(256), 0, stream>>>(k, khi2, klo2, v, vfrag);
        attn_fused_v7<<<dim3(2048), dim3(1024), 0, stream>>>(q, khi2, klo2, vfrag, mask, out, attn);
    } else {
        attn_fused_v1<<<dim3(2048), dim3(512), 0, stream>>>(q, k, v, mask, out, attn);
    }
}